// Round 2
// baseline (386.680 us; speedup 1.0000x reference)
//
#include <hip/hip_runtime.h>
#include <hip/hip_bf16.h>

typedef unsigned short u16;
typedef __attribute__((ext_vector_type(8))) short bf16x8;     // MFMA A/B frag: 8 bf16 = 4 VGPRs
typedef __attribute__((ext_vector_type(4))) float f32x4;      // MFMA C/D frag
typedef __attribute__((ext_vector_type(8))) unsigned short u16x8;

#define KD 1024
#define HD 1024
#define BM 128
#define BN 64
#define BK 32
#define NT (KD / BK)

__device__ __forceinline__ u16 f2b(float f) {
    return __builtin_bit_cast(u16, __float2bfloat16(f));
}

// ---- async global->LDS, 16B per lane, wave-uniform LDS base + lane*16 ----
__device__ __forceinline__ void gload16(const void* g, u16* smem, int lds_byte_off) {
    __builtin_amdgcn_global_load_lds(
        (const __attribute__((address_space(1))) void*)g,
        (__attribute__((address_space(3))) void*)((char*)smem + lds_byte_off),
        16, 0, 0);
}

// ---------------------------------------------------------------------------
// Kernel B: transpose+cast weights [g][k][n] f32 -> wt[g][n][k] bf16.
// K-contiguous rows enable ds_read_b128 B-fragments in the GEMM.
// ---------------------------------------------------------------------------
__global__ __launch_bounds__(256) void transpose_w(
    const float* __restrict__ wx, const float* __restrict__ wh, u16* __restrict__ wt)
{
    __shared__ u16 tile[64][65];   // +1 pad breaks bank collisions
    const int g = blockIdx.z;
    const float* src = (g < 3) ? (wx + (size_t)g * KD * HD) : (wh + (size_t)(g - 3) * KD * HD);
    u16* dst = wt + (size_t)g * KD * HD;
    const int r0 = blockIdx.y * 64;   // k rows in src
    const int c0 = blockIdx.x * 64;   // n cols in src
    const int t = threadIdx.x;

    #pragma unroll
    for (int r = 0; r < 2; r++) {
        int idx = r * 256 + t;
        int row = idx >> 3, cc = idx & 7;
        const float* p = src + (size_t)(r0 + row) * HD + c0 + cc * 8;
        #pragma unroll
        for (int e = 0; e < 8; e++) tile[row][cc * 8 + e] = f2b(p[e]);
    }
    __syncthreads();
    #pragma unroll
    for (int r = 0; r < 2; r++) {
        int idx = r * 256 + t;
        int nrow = idx >> 3, kc = idx & 7;
        u16x8 v;
        #pragma unroll
        for (int e = 0; e < 8; e++) v[e] = tile[kc * 8 + e][nrow];
        *(u16x8*)(dst + (size_t)(c0 + nrow) * KD + r0 + kc * 8) = v;
    }
}

// ---------------------------------------------------------------------------
// Epilogue. C/D layout: col=lane&15, row=quad*4+r (verified working config).
// ---------------------------------------------------------------------------
__device__ __forceinline__ void gru_epilogue(
    f32x4 (&acc)[4][4][2], const float* __restrict__ bxf, const float* __restrict__ bhf,
    const float* __restrict__ hidf, float* __restrict__ outf,
    int m0, int n0, int wm, int wn, int quad, int c16)
{
    float bR[2], bZ[2], bXN[2], bHN[2];
    #pragma unroll
    for (int j = 0; j < 2; j++) {
        int col = n0 + wn * 32 + j * 16 + c16;
        bR[j]  = bxf[col]          + bhf[col];
        bZ[j]  = bxf[HD + col]     + bhf[HD + col];
        bXN[j] = bxf[2 * HD + col];
        bHN[j] = bhf[2 * HD + col];
    }
    #pragma unroll
    for (int i = 0; i < 4; i++)
        #pragma unroll
        for (int j = 0; j < 2; j++) {
            int col = n0 + wn * 32 + j * 16 + c16;
            #pragma unroll
            for (int r = 0; r < 4; r++) {
                int row = m0 + wm * 64 + i * 16 + quad * 4 + r;
                size_t idx = (size_t)row * HD + col;
                float vr = acc[0][i][j][r] + bR[j];
                vr = 1.f / (1.f + __expf(-vr));
                float vz = acc[1][i][j][r] + bZ[j];
                vz = 1.f / (1.f + __expf(-vz));
                float vn = (acc[2][i][j][r] + bXN[j]) + vr * (acc[3][i][j][r] + bHN[j]);
                float e2 = __expf(2.f * vn);
                vn = 1.f - 2.f / (e2 + 1.f);
                float o = (1.f - vz) * vn + vz * hidf[idx];
                outf[idx] = o;
            }
        }
}

// ---- pack 8 f32 -> bf16x8 fragment (compiler fuses into v_cvt_pk) ----
__device__ __forceinline__ bf16x8 cvt8(const float4& a, const float4& b) {
    bf16x8 r;
    r[0] = (short)f2b(a.x); r[1] = (short)f2b(a.y);
    r[2] = (short)f2b(a.z); r[3] = (short)f2b(a.w);
    r[4] = (short)f2b(b.x); r[5] = (short)f2b(b.y);
    r[6] = (short)f2b(b.z); r[7] = (short)f2b(b.w);
    return r;
}

// ---------------------------------------------------------------------------
// MFMA block for one K-step. B (weights) read from LDS with the XOR swizzle:
// physical 16B slot = logical_quad ^ ((row>>1)&3). With this, the 16 lanes of
// a quad-group spread over 8 banks at 2 lanes/bank (2-way = free) instead of
// the unswizzled 8-way conflict (row stride 64 B -> banks {0,16} only).
// ---------------------------------------------------------------------------
__device__ __forceinline__ void kstep_mfma(
    const u16* sm, const bf16x8 (&ax)[4], const bf16x8 (&ah)[4],
    f32x4 (&acc)[4][4][2], int wn, int quad, int c16)
{
    #pragma unroll
    for (int p = 0; p < 3; p++) {
        bf16x8 bwx[2], bwh[2];
        #pragma unroll
        for (int j = 0; j < 2; j++) {
            int nl = wn * 32 + j * 16 + c16;
            int slot = (quad ^ ((nl >> 1) & 3)) * 8;
            bwx[j] = *(const bf16x8*)&sm[p * 2048       + nl * BK + slot];
            bwh[j] = *(const bf16x8*)&sm[(p + 3) * 2048 + nl * BK + slot];
        }
        #pragma unroll
        for (int i = 0; i < 4; i++)
            #pragma unroll
            for (int j = 0; j < 2; j++) {
                if (p < 2) {
                    acc[p][i][j] = __builtin_amdgcn_mfma_f32_16x16x32_bf16(ax[i], bwx[j], acc[p][i][j], 0, 0, 0);
                    acc[p][i][j] = __builtin_amdgcn_mfma_f32_16x16x32_bf16(ah[i], bwh[j], acc[p][i][j], 0, 0, 0);
                } else {
                    acc[2][i][j] = __builtin_amdgcn_mfma_f32_16x16x32_bf16(ax[i], bwx[j], acc[2][i][j], 0, 0, 0);
                    acc[3][i][j] = __builtin_amdgcn_mfma_f32_16x16x32_bf16(ah[i], bwh[j], acc[3][i][j], 0, 0, 0);
                }
            }
    }
}

// ---------------------------------------------------------------------------
// Fused GRU GEMM. Per K-step:
//   - A (x,h) fragments come straight from GLOBAL as f32 (prefetched one step
//     ahead into registers, converted to bf16 after the barrier that drained
//     them). No LDS, no convert_xh pre-pass, no barrier dependency.
//   - B (weights) double-buffered via global_load_lds (24 KB/buffer), source
//     pre-swizzled so the swizzled ds_read is conflict-free (rule: swizzle
//     both sides or neither — gload_lds dest is linear).
//   - ONE __syncthreads per K-step; its vmcnt(0) drain covers next-step
//     weight staging AND next-step A loads, all issued before ~700 cy of
//     ds_read+MFMA work.
// LDS: 2 x 24576 B = 48 KiB. Occupancy: 2 blocks/CU (VGPR-limited).
// ---------------------------------------------------------------------------
__global__ __launch_bounds__(256, 2) void gru_fused(
    const float* __restrict__ xf, const float* __restrict__ hf,
    const u16* __restrict__ wt,
    const float* __restrict__ bxf, const float* __restrict__ bhf,
    float* __restrict__ outf)
{
    __shared__ u16 smem[24576];   // 48 KiB: two 24 KiB weight buffers
    const int t    = threadIdx.x;
    const int lane = t & 63;
    const int w    = t >> 6;
    const int wm   = w >> 1, wn = w & 1;
    const int quad = lane >> 4;
    const int c16  = lane & 15;
    // XCD swizzle: linear % 8 presumed XCD; give each XCD 2 n-blocks so its
    // 1.57 MB weight slice stays L2-resident.
    const int lin  = blockIdx.x;
    const int nblk = (lin & 7) * 2 + ((lin >> 3) & 1);
    const int mblk = lin >> 4;
    const int m0   = mblk * BM;
    const int n0   = nblk * BN;

    // Weight staging: lane t writes LDS bytes [t*16, t*16+16) of a gate slab,
    // i.e. physical (row = t>>2, slot = t&3). For physical slot q to hold
    // logical slot q ^ ((row>>1)&3), the global source k-slot is
    // (t&3) ^ ((t>>3)&3)  (XOR is an involution).
    const int row4 = t >> 2;
    const int e8s  = ((t & 3) ^ ((t >> 3) & 3)) * 8;
    const u16* gw0 = wt + (size_t)(n0 + row4) * KD + e8s;
    const int ldsl = w * 1024;   // wave-uniform LDS byte base (lane adds *16)

    // A-operand per-lane f32 global base: row = m0 + wm*64 + i*16 + c16,
    // k = k0 + quad*8 (8 floats = 32 B = two float4 loads per fragment).
    const float* pax = xf + (size_t)(m0 + wm * 64 + c16) * KD + quad * 8;
    const float* pah = hf + (size_t)(m0 + wm * 64 + c16) * KD + quad * 8;

    f32x4 acc[4][4][2];
    #pragma unroll
    for (int a = 0; a < 4; a++)
        #pragma unroll
        for (int i = 0; i < 4; i++)
            #pragma unroll
            for (int j = 0; j < 2; j++)
                acc[a][i][j] = (f32x4){0.f, 0.f, 0.f, 0.f};

    float4 afx[4][2], afh[4][2];   // f32 A staging (one K-step ahead)

    auto loadA = [&](int koff) {
        #pragma unroll
        for (int i = 0; i < 4; i++) {
            const float* px = pax + (size_t)i * 16 * KD + koff;
            const float* ph = pah + (size_t)i * 16 * KD + koff;
            afx[i][0] = *(const float4*)px;
            afx[i][1] = *(const float4*)(px + 4);
            afh[i][0] = *(const float4*)ph;
            afh[i][1] = *(const float4*)(ph + 4);
        }
    };
    auto stageW = [&](const u16* gw, int bufb) {
        #pragma unroll
        for (int g = 0; g < 6; g++)
            gload16(gw + (size_t)g * KD * HD, smem, bufb + g * 4096 + ldsl);
    };

    // prologue: A(0) -> regs, W(0) -> buf0, drain both, barrier
    loadA(0);
    stageW(gw0, 0);
    gw0 += BK;
    __syncthreads();

    for (int tt = 0; tt < NT - 1; ++tt) {
        // A(tt) was drained by the previous barrier: convert to fragments,
        // freeing the f32 staging registers for the next prefetch.
        bf16x8 ax[4], ah[4];
        #pragma unroll
        for (int i = 0; i < 4; i++) {
            ax[i] = cvt8(afx[i][0], afx[i][1]);
            ah[i] = cvt8(afh[i][0], afh[i][1]);
        }
        // prefetch A(tt+1) and W(tt+1); both drained by the barrier below,
        // their latency hidden under this step's ds_read + MFMA work.
        loadA((tt + 1) * BK);
        stageW(gw0, ((tt + 1) & 1) * 24576);
        gw0 += BK;
        // compute step tt from buf[tt&1]
        kstep_mfma(smem + (tt & 1) * 12288, ax, ah, acc, wn, quad, c16);
        __syncthreads();
    }
    // final K-step: buffer (NT-1)&1 == 1, A already in staging regs
    {
        bf16x8 ax[4], ah[4];
        #pragma unroll
        for (int i = 0; i < 4; i++) {
            ax[i] = cvt8(afx[i][0], afx[i][1]);
            ah[i] = cvt8(afh[i][0], afh[i][1]);
        }
        kstep_mfma(smem + 12288, ax, ah, acc, wn, quad, c16);
    }

    gru_epilogue(acc, bxf, bhf, hf, outf, m0, n0, wm, wn, quad, c16);
}

extern "C" void kernel_launch(void* const* d_in, const int* in_sizes, int n_in,
                              void* d_out, int out_size, void* d_ws, size_t ws_size,
                              hipStream_t stream) {
    const float* x   = (const float*)d_in[0];
    const float* hid = (const float*)d_in[1];
    const float* wx  = (const float*)d_in[2];
    const float* wh  = (const float*)d_in[3];
    const float* bx  = (const float*)d_in[4];
    const float* bh  = (const float*)d_in[5];
    float* out = (float*)d_out;

    u16* wt = (u16*)d_ws;   // 12.6 MB of workspace for transposed bf16 weights

    dim3 tgrid(HD / 64, KD / 64, 6);
    transpose_w<<<tgrid, 256, 0, stream>>>(wx, wh, wt);
    gru_fused<<<1024, 256, 0, stream>>>(x, hid, wt, bx, bh, out);
}

// Round 3
// 239.145 us; speedup vs baseline: 1.6169x; 1.6169x over previous
//
#include <hip/hip_runtime.h>
#include <hip/hip_bf16.h>

typedef __hip_bfloat16 bf16;
typedef unsigned short u16;
typedef __attribute__((ext_vector_type(8))) short bf16x8;     // MFMA A/B frag: 8 bf16 = 4 VGPRs
typedef __attribute__((ext_vector_type(4))) float f32x4;      // MFMA C/D frag
typedef __attribute__((ext_vector_type(8))) unsigned short u16x8;

#define KD 1024
#define HD 1024
#define BSZ 8192
#define BM 128
#define BN 64
#define BK 32

// ws layout (bytes): wt [0, 12582912) | xb [12582912, +16777216) | hb [29360128, +16777216)
#define WS_XB 12582912
#define WS_HB 29360128
#define WS_NEED 46137344ULL

__device__ __forceinline__ u16 f2b(float f) {
    return __builtin_bit_cast(u16, __float2bfloat16(f));
}

// ---- async global->LDS, 16B per lane, wave-uniform LDS base + lane*16 ----
__device__ __forceinline__ void gload16(const void* g, u16* smem, int lds_byte_off) {
    __builtin_amdgcn_global_load_lds(
        (const __attribute__((address_space(1))) void*)g,
        (__attribute__((address_space(3))) void*)((char*)smem + lds_byte_off),
        16, 0, 0);
}

// ---------------------------------------------------------------------------
// Kernel A: one-shot f32 -> bf16 conversion of x and hid.
// ---------------------------------------------------------------------------
__global__ __launch_bounds__(256) void convert_xh(
    const float* __restrict__ x, const float* __restrict__ h,
    u16* __restrict__ xb, u16* __restrict__ hb)
{
    size_t off = ((size_t)blockIdx.x * 256 + threadIdx.x) * 8;   // <<<4096,256>>> covers 8M elems
    float4 a0 = *(const float4*)(x + off);
    float4 a1 = *(const float4*)(x + off + 4);
    float4 b0 = *(const float4*)(h + off);
    float4 b1 = *(const float4*)(h + off + 4);
    u16x8 vx, vh;
    vx[0]=f2b(a0.x); vx[1]=f2b(a0.y); vx[2]=f2b(a0.z); vx[3]=f2b(a0.w);
    vx[4]=f2b(a1.x); vx[5]=f2b(a1.y); vx[6]=f2b(a1.z); vx[7]=f2b(a1.w);
    vh[0]=f2b(b0.x); vh[1]=f2b(b0.y); vh[2]=f2b(b0.z); vh[3]=f2b(b0.w);
    vh[4]=f2b(b1.x); vh[5]=f2b(b1.y); vh[6]=f2b(b1.z); vh[7]=f2b(b1.w);
    *(u16x8*)(xb + off) = vx;
    *(u16x8*)(hb + off) = vh;
}

// ---------------------------------------------------------------------------
// Kernel B: transpose+cast weights [g][k][n] f32 -> wt[g][n][k] bf16.
// ---------------------------------------------------------------------------
__global__ __launch_bounds__(256) void transpose_w(
    const float* __restrict__ wx, const float* __restrict__ wh, u16* __restrict__ wt)
{
    __shared__ u16 tile[64][65];   // +1 pad breaks bank collisions
    const int g = blockIdx.z;
    const float* src = (g < 3) ? (wx + (size_t)g * KD * HD) : (wh + (size_t)(g - 3) * KD * HD);
    u16* dst = wt + (size_t)g * KD * HD;
    const int r0 = blockIdx.y * 64;   // k rows in src
    const int c0 = blockIdx.x * 64;   // n cols in src
    const int t = threadIdx.x;

    #pragma unroll
    for (int r = 0; r < 2; r++) {
        int idx = r * 256 + t;
        int row = idx >> 3, cc = idx & 7;
        const float* p = src + (size_t)(r0 + row) * HD + c0 + cc * 8;
        #pragma unroll
        for (int e = 0; e < 8; e++) tile[row][cc * 8 + e] = f2b(p[e]);
    }
    __syncthreads();
    #pragma unroll
    for (int r = 0; r < 2; r++) {
        int idx = r * 256 + t;
        int nrow = idx >> 3, kc = idx & 7;
        u16x8 v;
        #pragma unroll
        for (int e = 0; e < 8; e++) v[e] = tile[kc * 8 + e][nrow];
        *(u16x8*)(dst + (size_t)(c0 + nrow) * KD + r0 + kc * 8) = v;
    }
}

// ---------------------------------------------------------------------------
// Epilogue. C/D layout: col=lane&15, row=quad*4+r.
// ---------------------------------------------------------------------------
__device__ __forceinline__ void gru_epilogue(
    f32x4 (&acc)[4][4][2], const float* __restrict__ bxf, const float* __restrict__ bhf,
    const float* __restrict__ hidf, float* __restrict__ outf,
    int m0, int n0, int wm, int wn, int quad, int c16)
{
    float bR[2], bZ[2], bXN[2], bHN[2];
    #pragma unroll
    for (int j = 0; j < 2; j++) {
        int col = n0 + wn * 32 + j * 16 + c16;
        bR[j]  = bxf[col]          + bhf[col];
        bZ[j]  = bxf[HD + col]     + bhf[HD + col];
        bXN[j] = bxf[2 * HD + col];
        bHN[j] = bhf[2 * HD + col];
    }
    #pragma unroll
    for (int i = 0; i < 4; i++)
        #pragma unroll
        for (int j = 0; j < 2; j++) {
            int col = n0 + wn * 32 + j * 16 + c16;
            #pragma unroll
            for (int r = 0; r < 4; r++) {
                int row = m0 + wm * 64 + i * 16 + quad * 4 + r;
                size_t idx = (size_t)row * HD + col;
                float vr = acc[0][i][j][r] + bR[j];
                vr = 1.f / (1.f + __expf(-vr));
                float vz = acc[1][i][j][r] + bZ[j];
                vz = 1.f / (1.f + __expf(-vz));
                float vn = (acc[2][i][j][r] + bXN[j]) + vr * (acc[3][i][j][r] + bHN[j]);
                float e2 = __expf(2.f * vn);
                vn = 1.f - 2.f / (e2 + 1.f);
                float o = (1.f - vz) * vn + vz * hidf[idx];
                outf[idx] = o;
            }
        }
}

// ---------------------------------------------------------------------------
// Stage one K-step (BK=32) tile set into LDS buffer at byte base `bufb`.
// Layout within buffer (bytes): x0 [0,4K) x1 [4K,8K) h0 [8K,12K) h1 [12K,16K)
// w[g] at 16K + g*4K. Total 40960 B per buffer.
// The global source pointers are PRE-SWIZZLED (16B k-slot XOR'd with row
// bits) so the linear global_load_lds write produces the swizzled layout
// (rule #21: swizzle both sides — gload_lds dest is wave-uniform linear).
// ---------------------------------------------------------------------------
__device__ __forceinline__ void kstep_stage(
    const u16* gx0, const u16* gx1, const u16* gh0, const u16* gh1,
    const u16* gw0, u16* smem, int bufb, int ldsl)
{
    gload16(gx0, smem, bufb + ldsl);
    gload16(gx1, smem, bufb + 4096 + ldsl);
    gload16(gh0, smem, bufb + 8192 + ldsl);
    gload16(gh1, smem, bufb + 12288 + ldsl);
    #pragma unroll
    for (int g = 0; g < 6; g++)
        gload16(gw0 + (size_t)g * KD * HD, smem, bufb + 16384 + g * 4096 + ldsl);
}

// ---------------------------------------------------------------------------
// Compute one K-step from LDS buffer at u16 pointer sm. All reads use the
// slot XOR  phys_slot = quad ^ ((row>>1)&3 : with this, a wave's 64 lanes
// spread a ds_read_b128 over all 32 banks at the theoretical-minimum 8
// touches/bank instead of the unswizzled 8-way collision (row stride 64 B
// put all 16 c16-lanes on banks {0,16}+quad*4). Verified conflicts->0 in R2.
// ---------------------------------------------------------------------------
__device__ __forceinline__ void kstep_compute(
    const u16* sm, f32x4 (&acc)[4][4][2], int wm, int wn, int quad, int c16)
{
    bf16x8 ax[4], ah[4];
    #pragma unroll
    for (int i = 0; i < 4; i++) {
        int ml = wm * 64 + i * 16 + c16;
        int sl = (quad ^ ((ml >> 1) & 3)) * 8;
        ax[i] = *(const bf16x8*)&sm[ml * BK + sl];
        ah[i] = *(const bf16x8*)&sm[4096 + ml * BK + sl];
    }
    #pragma unroll
    for (int p = 0; p < 3; p++) {
        bf16x8 bwx[2], bwh[2];
        #pragma unroll
        for (int j = 0; j < 2; j++) {
            int nl = wn * 32 + j * 16 + c16;
            int sl = (quad ^ ((nl >> 1) & 3)) * 8;
            bwx[j] = *(const bf16x8*)&sm[8192 + p * 2048       + nl * BK + sl];
            bwh[j] = *(const bf16x8*)&sm[8192 + (p + 3) * 2048 + nl * BK + sl];
        }
        #pragma unroll
        for (int i = 0; i < 4; i++)
            #pragma unroll
            for (int j = 0; j < 2; j++) {
                if (p < 2) {
                    acc[p][i][j] = __builtin_amdgcn_mfma_f32_16x16x32_bf16(ax[i], bwx[j], acc[p][i][j], 0, 0, 0);
                    acc[p][i][j] = __builtin_amdgcn_mfma_f32_16x16x32_bf16(ah[i], bwh[j], acc[p][i][j], 0, 0, 0);
                } else {
                    acc[2][i][j] = __builtin_amdgcn_mfma_f32_16x16x32_bf16(ax[i], bwx[j], acc[2][i][j], 0, 0, 0);
                    acc[3][i][j] = __builtin_amdgcn_mfma_f32_16x16x32_bf16(ah[i], bwh[j], acc[3][i][j], 0, 0, 0);
                }
            }
    }
}

// ---------------------------------------------------------------------------
// Kernel C (fast): R1's double-buffered 2-phase pipeline + full LDS swizzle.
// Per K-step: issue next-tile global_load_lds FIRST, then ds_read+MFMA the
// current buffer, then ONE __syncthreads(). LDS = 2 x 40960 B = 80 KiB.
// ---------------------------------------------------------------------------
__global__ __launch_bounds__(256, 2) void gru_fused_fast(
    const u16* __restrict__ xb, const u16* __restrict__ hb,
    const u16* __restrict__ wt,
    const float* __restrict__ bxf, const float* __restrict__ bhf,
    const float* __restrict__ hidf, float* __restrict__ outf)
{
    __shared__ u16 smem[40960];   // 80 KiB: two 40960-byte buffers
    const int t    = threadIdx.x;
    const int lane = t & 63;
    const int w    = t >> 6;
    const int wm   = w >> 1, wn = w & 1;
    const int quad = lane >> 4;
    const int c16  = lane & 15;
    // XCD swizzle: linear % 8 presumed XCD; give each XCD 2 n-blocks so its
    // 1.57 MB weight slice stays L2-resident.
    const int lin  = blockIdx.x;
    const int nblk = (lin & 7) * 2 + ((lin >> 3) & 1);
    const int mblk = lin >> 4;
    const int m0   = mblk * BM;
    const int n0   = nblk * BN;

    // Staging geometry: lane t writes LDS (row = t>>2, 16B-slot = t&3) of a
    // 64-row x 32-k tile. Source k-slot is XOR'd so physical slot p holds
    // logical slot p ^ ((row>>1)&3)  (involution; read side applies same XOR).
    const int row4 = t >> 2;
    const int e8s  = ((t & 3) ^ ((t >> 3) & 3)) * 8;
    const u16* gx0 = xb + (size_t)(m0 + row4) * KD + e8s;
    const u16* gx1 = gx0 + (size_t)64 * KD;
    const u16* gh0 = hb + (size_t)(m0 + row4) * KD + e8s;
    const u16* gh1 = gh0 + (size_t)64 * KD;
    const u16* gw0 = wt + (size_t)(n0 + row4) * KD + e8s;
    const int ldsl = w * 1024;   // wave-uniform LDS byte base (lane adds *16)

    f32x4 acc[4][4][2];
    #pragma unroll
    for (int a = 0; a < 4; a++)
        #pragma unroll
        for (int i = 0; i < 4; i++)
            #pragma unroll
            for (int j = 0; j < 2; j++)
                acc[a][i][j] = (f32x4){0.f, 0.f, 0.f, 0.f};

    const int NT = KD / BK;   // 32

    // prologue: stage k-step 0 into buffer 0, drain, barrier
    kstep_stage(gx0, gx1, gh0, gh1, gw0, smem, 0, ldsl);
    gx0 += BK; gx1 += BK; gh0 += BK; gh1 += BK; gw0 += BK;
    __syncthreads();

    // steady state: stage t+1 into buf[(t+1)&1] while computing t from buf[t&1].
    for (int tt = 0; tt < NT - 1; ++tt) {
        kstep_stage(gx0, gx1, gh0, gh1, gw0, smem, ((tt + 1) & 1) * 40960, ldsl);
        gx0 += BK; gx1 += BK; gh0 += BK; gh1 += BK; gw0 += BK;
        kstep_compute(smem + (tt & 1) * 20480, acc, wm, wn, quad, c16);
        __syncthreads();
    }
    // epilogue K-step: buffer (NT-1)&1 == 1, staged and drained by last iter
    kstep_compute(smem + 20480, acc, wm, wn, quad, c16);

    gru_epilogue(acc, bxf, bhf, hidf, outf, m0, n0, wm, wn, quad, c16);
}

// ---------------------------------------------------------------------------
// Kernel C' (fallback if ws too small for xb/hb): in-loop f32->bf16 convert
// for x/h (ds_write to the swizzled slot); weights via pre-swizzled
// global_load_lds. Single-buffer, two barriers per step.
// ---------------------------------------------------------------------------
__global__ __launch_bounds__(256, 2) void gru_fused_slow(
    const float* __restrict__ xf, const float* __restrict__ hf,
    const u16* __restrict__ wt,
    const float* __restrict__ bxf, const float* __restrict__ bhf,
    float* __restrict__ outf)
{
    __shared__ u16 smem[20480];
    const int t    = threadIdx.x;
    const int lane = t & 63;
    const int w    = t >> 6;
    const int wm   = w >> 1, wn = w & 1;
    const int quad = lane >> 4;
    const int c16  = lane & 15;
    const int lin  = blockIdx.x;
    const int nblk = (lin & 7) * 2 + ((lin >> 3) & 1);
    const int mblk = lin >> 4;
    const int m0   = mblk * BM;
    const int n0   = nblk * BN;
    const int row4 = t >> 2;
    const int e8s  = ((t & 3) ^ ((t >> 3) & 3)) * 8;
    const int sls  = e8s;   // physical u16 slot offset for swizzled ds_write
    const u16* gw0 = wt + (size_t)(n0 + row4) * KD + e8s;
    const int ldsl = w * 1024;

    f32x4 acc[4][4][2];
    #pragma unroll
    for (int a = 0; a < 4; a++)
        #pragma unroll
        for (int i = 0; i < 4; i++)
            #pragma unroll
            for (int j = 0; j < 2; j++)
                acc[a][i][j] = (f32x4){0.f, 0.f, 0.f, 0.f};

    for (int k0 = 0; k0 < KD; k0 += BK) {
        #pragma unroll
        for (int g = 0; g < 6; g++)
            gload16(gw0 + (size_t)g * KD * HD, smem, 16384 + g * 4096 + ldsl);
        gw0 += BK;
        #pragma unroll
        for (int s = 0; s < 2; s++) {
            // load LOGICAL k-slot (t&3), write to the swizzled physical slot
            size_t gidx = (size_t)(m0 + s * 64 + row4) * KD + k0 + (t & 3) * 8;
            const float* px = xf + gidx;
            const float* ph = hf + gidx;
            u16x8 vx, vh;
            #pragma unroll
            for (int e = 0; e < 8; e++) { vx[e] = f2b(px[e]); vh[e] = f2b(ph[e]); }
            *(u16x8*)&smem[s * 2048 + row4 * 32 + sls] = vx;
            *(u16x8*)&smem[4096 + s * 2048 + row4 * 32 + sls] = vh;
        }
        __syncthreads();
        kstep_compute(smem, acc, wm, wn, quad, c16);
        __syncthreads();
    }

    gru_epilogue(acc, bxf, bhf, hf, outf, m0, n0, wm, wn, quad, c16);
}

extern "C" void kernel_launch(void* const* d_in, const int* in_sizes, int n_in,
                              void* d_out, int out_size, void* d_ws, size_t ws_size,
                              hipStream_t stream) {
    const float* x   = (const float*)d_in[0];
    const float* hid = (const float*)d_in[1];
    const float* wx  = (const float*)d_in[2];
    const float* wh  = (const float*)d_in[3];
    const float* bx  = (const float*)d_in[4];
    const float* bh  = (const float*)d_in[5];
    float* out = (float*)d_out;

    char* ws = (char*)d_ws;
    u16* wt = (u16*)ws;
    u16* xb = (u16*)(ws + WS_XB);
    u16* hb = (u16*)(ws + WS_HB);

    dim3 tgrid(HD / 64, KD / 64, 6);
    transpose_w<<<tgrid, 256, 0, stream>>>(wx, wh, wt);

    if (ws_size >= WS_NEED) {
        convert_xh<<<4096, 256, 0, stream>>>(x, hid, xb, hb);
        gru_fused_fast<<<1024, 256, 0, stream>>>(xb, hb, wt, bx, bh, hid, out);
    } else {
        gru_fused_slow<<<1024, 256, 0, stream>>>(x, hid, wt, bx, bh, out);
    }
}